// Round 7
// baseline (413.881 us; speedup 1.0000x reference)
//
#include <hip/hip_runtime.h>

typedef __bf16 bf16_t;
typedef __bf16 bf16x2 __attribute__((ext_vector_type(2)));
typedef __bf16 bf16x8 __attribute__((ext_vector_type(8)));
typedef float floatx4 __attribute__((ext_vector_type(4)));

#define B_ 4
#define S_ 4096
#define D_ 1024
#define H_ 16
#define HD_ 64
#define M_TOT (B_ * S_)   // 16384

#define BM 128
#define BN 128
#define BK 64

__device__ __forceinline__ void async_load16(const bf16_t* g, bf16_t* l) {
  __builtin_amdgcn_global_load_lds(
      (const __attribute__((address_space(1))) void*)g,
      (__attribute__((address_space(3))) void*)l,
      16, 0, 0);
}

// ---------------- fused prep: casts + weight transposes + workspace zeroing ----------------
struct PrepArgs {
  const float* q; const float* kv;
  bf16_t* aq; bf16_t* akv;
  const float* w0; const float* w1; const float* w2; const float* w3;
  bf16_t* t0; bf16_t* t1; bf16_t* t2; bf16_t* t3;
  float* zbase;
};

__global__ __launch_bounds__(256) void prep_kernel(PrepArgs p) {
  __shared__ float tile[32][33];
  const int bid = blockIdx.x;
  const int t = threadIdx.x;
  if (bid < 16384) {
    const float* in = bid < 8192 ? p.q : p.kv;
    bf16_t* out = bid < 8192 ? p.aq : p.akv;
    int i = ((bid & 8191) * 256 + t) * 8;
    float4 a = *(const float4*)(in + i);
    float4 b = *(const float4*)(in + i + 4);
    bf16x8 o;
    o[0] = (bf16_t)a.x; o[1] = (bf16_t)a.y; o[2] = (bf16_t)a.z; o[3] = (bf16_t)a.w;
    o[4] = (bf16_t)b.x; o[5] = (bf16_t)b.y; o[6] = (bf16_t)b.z; o[7] = (bf16_t)b.w;
    *(bf16x8*)(out + i) = o;
  } else if (bid < 20480) {
    int idx = bid - 16384;
    int z = idx >> 10;
    int rem = idx & 1023;
    const float* W = z == 0 ? p.w0 : z == 1 ? p.w1 : z == 2 ? p.w2 : p.w3;
    bf16_t* Wt = z == 0 ? p.t0 : z == 1 ? p.t1 : z == 2 ? p.t2 : p.t3;
    int n0 = (rem & 31) * 32;
    int k0 = (rem >> 5) * 32;
    int tx = t & 31;
    int ty = t >> 5;  // 0..7
    for (int r = ty; r < 32; r += 8)
      tile[r][tx] = W[(size_t)(k0 + r) * D_ + n0 + tx];
    __syncthreads();
    for (int r = ty; r < 32; r += 8)
      Wt[(size_t)(n0 + r) * D_ + k0 + tx] = (bf16_t)tile[tx][r];
  } else {
    int idx = bid - 20480;  // 0..259 ; 260*256 float4 = 1MB + 16KB
    ((float4*)p.zbase)[idx * 256 + t] = (float4){0.f, 0.f, 0.f, 0.f};
  }
}

// ---------------- bf16 MFMA GEMM (R5-verified): C[m][n] = sum_k A[m][k]*Bt[n][k] + bias ----
// LDS XOR-swizzled at 16B-chunk granularity (0 bank conflicts, measured R5).
// mode 1: elu(x)+1, store bf16.  mode 2: bias, store fp32.
// mode 3: dual: n<1024 -> elu+1 into outb, n>=1024 -> bias2 into outb2.
__global__ __launch_bounds__(256) void gemm_bt_kernel(
    const bf16_t* __restrict__ A,    // M x K
    const bf16_t* __restrict__ Bt,   // N x K
    const float* __restrict__ bias,
    const float* __restrict__ bias2,
    bf16_t* __restrict__ outb,
    bf16_t* __restrict__ outb2,
    float* __restrict__ outf,
    int M, int N, int K, int mode) {
  __shared__ __attribute__((aligned(16))) bf16_t As[BM * BK];
  __shared__ __attribute__((aligned(16))) bf16_t Bs[BN * BK];
  const int t = threadIdx.x;
  const int w = t >> 6;
  const int lane = t & 63;

  // XCD-aware swizzle: blocks sharing an A m-tile land consecutively on one XCD.
  const int L = blockIdx.y * gridDim.x + blockIdx.x;
  const int nxl2 = 31 - __clz(gridDim.x);       // gridDim.x is a power of 2
  const int xcd = L & 7;
  const int slot = L >> 3;
  const int mt = xcd * (gridDim.y >> 3) + (slot >> nxl2);
  const int nt = slot & ((1 << nxl2) - 1);
  const int row0 = mt * BM;
  const int col0 = nt * BN;

  const int wm = (w & 1) * 64;
  const int wn = (w >> 1) * 64;
  const int lr = lane & 15;
  const int lq = lane >> 4;
  const int rx = lr & 7;  // fragment-read XOR key (row & 7)

  floatx4 acc[4][4];
#pragma unroll
  for (int i = 0; i < 4; ++i)
#pragma unroll
    for (int j = 0; j < 4; ++j) acc[i][j] = (floatx4){0.f, 0.f, 0.f, 0.f};

  for (int kt = 0; kt < K; kt += BK) {
#pragma unroll
    for (int j = 0; j < 4; ++j) {
      int s = j * 256 + t;                       // 16B-chunk slot in tile
      int r = s >> 3;                            // tile row
      int cs = (((s & 7) ^ (r & 7)) << 3);       // swizzled source column (elems)
      async_load16(&A[(size_t)(row0 + r) * K + kt + cs], &As[j * 2048 + w * 512]);
      async_load16(&Bt[(size_t)(col0 + r) * K + kt + cs], &Bs[j * 2048 + w * 512]);
    }
    __syncthreads();
#pragma unroll
    for (int ks = 0; ks < BK; ks += 32) {
      const int go = ((lq + (ks >> 3)) ^ rx) << 3;  // swizzled chunk offset (elems)
      bf16x8 af[4], bfr[4];
#pragma unroll
      for (int i = 0; i < 4; ++i)
        af[i] = *(const bf16x8*)&As[(wm + i * 16 + lr) * BK + go];
#pragma unroll
      for (int j = 0; j < 4; ++j)
        bfr[j] = *(const bf16x8*)&Bs[(wn + j * 16 + lr) * BK + go];
#pragma unroll
      for (int i = 0; i < 4; ++i)
#pragma unroll
        for (int j = 0; j < 4; ++j)
          acc[i][j] = __builtin_amdgcn_mfma_f32_16x16x32_bf16(af[i], bfr[j], acc[i][j], 0, 0, 0);
    }
    __syncthreads();
  }

#pragma unroll
  for (int i = 0; i < 4; ++i) {
#pragma unroll
    for (int j = 0; j < 4; ++j) {
      int gr = row0 + wm + i * 16 + lq * 4;
      int gc = col0 + wn + j * 16 + lr;
      if (mode == 3) {
        if (gc < 1024) {
          float bsv = bias[gc];
#pragma unroll
          for (int r = 0; r < 4; ++r) {
            float v = acc[i][j][r] + bsv;
            v = v > 0.f ? v + 1.f : __expf(v);
            outb[(size_t)(gr + r) * 1024 + gc] = (bf16_t)v;
          }
        } else {
          float bsv = bias2[gc - 1024];
#pragma unroll
          for (int r = 0; r < 4; ++r) {
            float v = acc[i][j][r] + bsv;
            outb2[(size_t)(gr + r) * 1024 + (gc - 1024)] = (bf16_t)v;
          }
        }
      } else {
        float bsv = bias[gc];
#pragma unroll
        for (int r = 0; r < 4; ++r) {
          float v = acc[i][j][r] + bsv;
          if (mode == 1) v = v > 0.f ? v + 1.f : __expf(v);
          if (mode == 2)
            outf[(size_t)(gr + r) * N + gc] = v;
          else
            outb[(size_t)(gr + r) * N + gc] = (bf16_t)v;
        }
      }
    }
  }
}

// ---------------- KV summarize (MFMA): KVt[bh][e][d] += sum_s V[s][e]*K[s][d]; Ksum[bh][d] ----------------
#define KVP 68  // LDS row stride (elems) for transposed tiles
__global__ __launch_bounds__(256) void kv_mfma_kernel(
    const bf16_t* __restrict__ Kf, const bf16_t* __restrict__ Vf,
    float* __restrict__ KVtg, float* __restrict__ Ksumg) {
  __shared__ __attribute__((aligned(16))) bf16_t Kt[64 * KVP];  // [d][s]
  __shared__ __attribute__((aligned(16))) bf16_t Vt[64 * KVP];  // [e][s]
  const int t = threadIdx.x;
  const int w = t >> 6, lane = t & 63;
  const int lr = lane & 15, lq = lane >> 4;
  const int bh = blockIdx.x, sc = blockIdx.y;
  const int b = bh >> 4, h = bh & 15;
  const size_t base = (size_t)b * S_ * D_ + (size_t)h * HD_;
  const int p = t >> 3;          // row-pair 0..31
  const int c0 = (t & 7) * 8;    // feature col 0..56

  floatx4 acc[4], accn[4];
#pragma unroll
  for (int j = 0; j < 4; ++j) {
    acc[j] = (floatx4){0.f, 0.f, 0.f, 0.f};
    accn[j] = (floatx4){0.f, 0.f, 0.f, 0.f};
  }
  bf16x8 ones;
#pragma unroll
  for (int u = 0; u < 8; ++u) ones[u] = (bf16_t)(lr == 0 ? 1.f : 0.f);

  for (int st = 0; st < 8; ++st) {  // 8 tiles x 64 s = 512 s
    int s0 = sc * 512 + st * 64;
    bf16x8 ka = *(const bf16x8*)&Kf[base + (size_t)(s0 + 2 * p) * D_ + c0];
    bf16x8 kb = *(const bf16x8*)&Kf[base + (size_t)(s0 + 2 * p + 1) * D_ + c0];
    bf16x8 va = *(const bf16x8*)&Vf[base + (size_t)(s0 + 2 * p) * D_ + c0];
    bf16x8 vb = *(const bf16x8*)&Vf[base + (size_t)(s0 + 2 * p + 1) * D_ + c0];
    __syncthreads();  // previous iter's reads done before overwriting LDS
#pragma unroll
    for (int u = 0; u < 8; ++u) {
      *(bf16x2*)&Kt[(c0 + u) * KVP + 2 * p] = (bf16x2){ka[u], kb[u]};
      *(bf16x2*)&Vt[(c0 + u) * KVP + 2 * p] = (bf16x2){va[u], vb[u]};
    }
    __syncthreads();
#pragma unroll
    for (int ks = 0; ks < 2; ++ks) {
      bf16x8 af = *(const bf16x8*)&Vt[(w * 16 + lr) * KVP + ks * 32 + lq * 8];
      bf16x8 bf_[4];
#pragma unroll
      for (int j = 0; j < 4; ++j)
        bf_[j] = *(const bf16x8*)&Kt[(j * 16 + lr) * KVP + ks * 32 + lq * 8];
#pragma unroll
      for (int j = 0; j < 4; ++j)
        acc[j] = __builtin_amdgcn_mfma_f32_16x16x32_bf16(af, bf_[j], acc[j], 0, 0, 0);
      if (w == 0) {
#pragma unroll
        for (int j = 0; j < 4; ++j)
          accn[j] = __builtin_amdgcn_mfma_f32_16x16x32_bf16(ones, bf_[j], accn[j], 0, 0, 0);
      }
    }
  }
  float* kvp = KVtg + (size_t)bh * 4096;
#pragma unroll
  for (int j = 0; j < 4; ++j)
#pragma unroll
    for (int r = 0; r < 4; ++r)
      atomicAdd(&kvp[(w * 16 + lq * 4 + r) * 64 + j * 16 + lr], acc[j][r]);
  if (w == 0 && lq == 0) {
#pragma unroll
    for (int j = 0; j < 4; ++j)
      atomicAdd(&Ksumg[bh * 64 + j * 16 + lr], accn[j][0]);
  }
}

// ---------------- attend (MFMA): X[b,q,h,:] = (Q . KV) / (Q . Ksum + 1e-6) ----------------
__global__ __launch_bounds__(256) void attend_mfma_kernel(
    const bf16_t* __restrict__ Qf, const float* __restrict__ KVtg,
    const float* __restrict__ Ksumg, bf16_t* __restrict__ X) {
  __shared__ __attribute__((aligned(16))) bf16_t As[256 * 64];  // 32KB
  __shared__ __attribute__((aligned(16))) bf16_t Bs[64 * 64];   // 8KB
  const int t = threadIdx.x;
  const int w = t >> 6;
  const int lane = t & 63;
  const int lr = lane & 15;
  const int lq = lane >> 4;
  const int rx = lr & 7;
  const int bh = blockIdx.y;
  const int b = bh >> 4, h = bh & 15;
  const int q0 = blockIdx.x * 256;
  const size_t qbase = ((size_t)b * S_ + q0) * D_ + (size_t)h * HD_;

  // stage Q rows via async LDS DMA (swizzled source chunk)
  {
    const int r8 = lane >> 3;
    const int cs = (((lane & 7) ^ (r8 & 7)) << 3);
#pragma unroll
    for (int it = 0; it < 8; ++it) {
      int r = w * 64 + it * 8 + r8;
      async_load16(&Qf[qbase + (size_t)r * D_ + cs], &As[(w * 64 + it * 8) * 64]);
    }
  }
  // stage KV^T: fp32 -> bf16 cast (KVtg is [e][d] row-major = exactly Bt layout), swizzled store
  {
    const float* src = KVtg + (size_t)bh * 4096;
    int i0 = t * 16;
    float4 f0 = *(const float4*)(src + i0);
    float4 f1 = *(const float4*)(src + i0 + 4);
    float4 f2 = *(const float4*)(src + i0 + 8);
    float4 f3 = *(const float4*)(src + i0 + 12);
    bf16x8 o1, o2;
    o1[0] = (bf16_t)f0.x; o1[1] = (bf16_t)f0.y; o1[2] = (bf16_t)f0.z; o1[3] = (bf16_t)f0.w;
    o1[4] = (bf16_t)f1.x; o1[5] = (bf16_t)f1.y; o1[6] = (bf16_t)f1.z; o1[7] = (bf16_t)f1.w;
    o2[0] = (bf16_t)f2.x; o2[1] = (bf16_t)f2.y; o2[2] = (bf16_t)f2.z; o2[3] = (bf16_t)f2.w;
    o2[4] = (bf16_t)f3.x; o2[5] = (bf16_t)f3.y; o2[6] = (bf16_t)f3.z; o2[7] = (bf16_t)f3.w;
    int r = t >> 2;
    int cc = (t & 3) * 2;
    int rxw = r & 7;
    *(bf16x8*)&Bs[r * 64 + ((cc ^ rxw) << 3)] = o1;
    *(bf16x8*)&Bs[r * 64 + (((cc + 1) ^ rxw) << 3)] = o2;
  }

  // norm B fragments: row n=0 holds Ksum (bf16), rows 1..15 zero
  bf16x8 bn[2];
#pragma unroll
  for (int ks = 0; ks < 2; ++ks) {
    bf16x8 z;
#pragma unroll
    for (int u = 0; u < 8; ++u) z[u] = (bf16_t)0.f;
    if (lr == 0) {
      const float* kp = &Ksumg[bh * 64 + ks * 32 + lq * 8];
      float4 k1 = *(const float4*)kp;
      float4 k2 = *(const float4*)(kp + 4);
      z[0] = (bf16_t)k1.x; z[1] = (bf16_t)k1.y; z[2] = (bf16_t)k1.z; z[3] = (bf16_t)k1.w;
      z[4] = (bf16_t)k2.x; z[5] = (bf16_t)k2.y; z[6] = (bf16_t)k2.z; z[7] = (bf16_t)k2.w;
    }
    bn[ks] = z;
  }

  floatx4 acc[4][4];
  floatx4 accn[4];
#pragma unroll
  for (int i = 0; i < 4; ++i) {
    accn[i] = (floatx4){0.f, 0.f, 0.f, 0.f};
#pragma unroll
    for (int j = 0; j < 4; ++j) acc[i][j] = (floatx4){0.f, 0.f, 0.f, 0.f};
  }

  __syncthreads();

#pragma unroll
  for (int ks = 0; ks < 2; ++ks) {
    // ks is a STEP INDEX here (chunk offset = ks*4)
    const int go = ((lq + ks * 4) ^ rx) << 3;
    bf16x8 af[4], bfr[4];
#pragma unroll
    for (int i = 0; i < 4; ++i)
      af[i] = *(const bf16x8*)&As[(w * 64 + i * 16 + lr) * 64 + go];
#pragma unroll
    for (int j = 0; j < 4; ++j)
      bfr[j] = *(const bf16x8*)&Bs[(j * 16 + lr) * 64 + go];
#pragma unroll
    for (int i = 0; i < 4; ++i) {
#pragma unroll
      for (int j = 0; j < 4; ++j)
        acc[i][j] = __builtin_amdgcn_mfma_f32_16x16x32_bf16(af[i], bfr[j], acc[i][j], 0, 0, 0);
      accn[i] = __builtin_amdgcn_mfma_f32_16x16x32_bf16(af[i], bn[ks], accn[i], 0, 0, 0);
    }
  }

  // epilogue: normalize and store bf16
#pragma unroll
  for (int i = 0; i < 4; ++i) {
    int rowb = q0 + w * 64 + i * 16 + lq * 4;
#pragma unroll
    for (int r = 0; r < 4; ++r) {
      float nr = __shfl(accn[i][r], lane & 48);  // norm lives on lane lr==0 of each lq group
      float inv = 1.f / (nr + 1e-6f);
      size_t rb = ((size_t)b * S_ + rowb + r) * D_ + (size_t)h * HD_;
#pragma unroll
      for (int j = 0; j < 4; ++j)
        X[rb + j * 16 + lr] = (bf16_t)(acc[i][j][r] * inv);
    }
  }
}

extern "C" void kernel_launch(void* const* d_in, const int* in_sizes, int n_in,
                              void* d_out, int out_size, void* d_ws, size_t ws_size,
                              hipStream_t stream) {
  const float* query     = (const float*)d_in[0];
  const float* key_value = (const float*)d_in[1];
  const float* Wq = (const float*)d_in[2];
  const float* bq = (const float*)d_in[3];
  const float* Wk = (const float*)d_in[4];
  const float* bk = (const float*)d_in[5];
  const float* Wv = (const float*)d_in[6];
  const float* bv = (const float*)d_in[7];
  const float* Wo = (const float*)d_in[8];
  const float* bo = (const float*)d_in[9];
  float* out = (float*)d_out;

  char* ws = (char*)d_ws;
  const size_t MB = 1024 * 1024;
  bf16_t* Aq   = (bf16_t*)(ws + 0);         // 32MB (query bf16; later reused as X)
  bf16_t* Akv  = (bf16_t*)(ws + 32 * MB);   // 32MB (key_value bf16)
  bf16_t* WqT  = (bf16_t*)(ws + 64 * MB);   // 2MB each
  bf16_t* WkT  = (bf16_t*)(ws + 66 * MB);   // WkT and WvT ADJACENT -> fused N=2048 B matrix
  bf16_t* WvT  = (bf16_t*)(ws + 68 * MB);
  bf16_t* WoT  = (bf16_t*)(ws + 70 * MB);
  bf16_t* Qf   = (bf16_t*)(ws + 72 * MB);   // 32MB
  bf16_t* Kf   = (bf16_t*)(ws + 104 * MB);  // 32MB
  bf16_t* Vf   = (bf16_t*)(ws + 136 * MB);  // 32MB
  float*  KVtg = (float*)(ws + 168 * MB);   // 1MB  (64 x [e][d] fp32)
  float*  Ksumg= (float*)(ws + 169 * MB);   // 16KB (contiguous after KVtg)

  // 1) prep: casts + transposes + zeroing, one launch
  PrepArgs pa = {query, key_value, Aq, Akv, Wq, Wk, Wv, Wo, WqT, WkT, WvT, WoT, KVtg};
  prep_kernel<<<20740, 256, 0, stream>>>(pa);

  // 2) Q projection GEMM (separate launch: keeps per-XCD weight working set = 2MB in L2)
  dim3 ggrid(D_ / BN, M_TOT / BM);       // (8, 128)
  gemm_bt_kernel<<<ggrid, 256, 0, stream>>>(Aq, WqT, bq, nullptr, Qf, nullptr, nullptr,
                                            M_TOT, D_, D_, 1);

  // 3) fused K+V projection GEMM (N=2048, dual epilogue)
  dim3 ggrid2(2 * D_ / BN, M_TOT / BM);  // (16, 128)
  gemm_bt_kernel<<<ggrid2, 256, 0, stream>>>(Akv, WkT, bk, bv, Kf, Vf, nullptr,
                                             M_TOT, 2 * D_, D_, 3);

  // 4) KV summarize
  dim3 kvgrid(64, 8);
  kv_mfma_kernel<<<kvgrid, 256, 0, stream>>>(Kf, Vf, KVtg, Ksumg);

  // 5) attend
  dim3 agrid(S_ / 256, 64);  // (16, 64)
  attend_mfma_kernel<<<agrid, 256, 0, stream>>>(Qf, KVtg, Ksumg, Aq /* X */);

  // 6) output projection (fp32 out)
  gemm_bt_kernel<<<ggrid, 256, 0, stream>>>(Aq, WoT, bo, nullptr, nullptr, nullptr, out,
                                            M_TOT, D_, D_, 2);
}